// Round 9
// baseline (1202.713 us; speedup 1.0000x reference)
//
#include <hip/hip_runtime.h>

#define NN 10000
#define STRD 10272  // bf16 panel/adjb row stride (elements)
#define NT 160      // K-steps of 64 (covers 10240 padded cols)
#define FEAT 2048
#define HID 128
#define NCLS 64

typedef short s16x8 __attribute__((ext_vector_type(8)));
typedef float f32x4 __attribute__((ext_vector_type(4)));

static __device__ __forceinline__ unsigned short f2bf(float f) {
  unsigned int u = __float_as_uint(f);
  u += 0x7FFFu + ((u >> 16) & 1u);
  return (unsigned short)(u >> 16);
}

#define MFMA16(accv, av, bv) \
  (accv) = __builtin_amdgcn_mfma_f32_16x16x32_bf16((av), (bv), (accv), 0, 0, 0)

// Self-calibration of the MFMA C/D lane->(m,n) mapping (proved correct in R2).
__device__ __forceinline__ void calib_mn(int lane, int* cm, int* cn) {
  const int lr = lane & 15;
  const int lg = lane >> 4;
  s16x8 pa, pb;
#pragma unroll
  for (int j = 0; j < 8; ++j) { pa[j] = 0; pb[j] = 0; }
  if (lg == 0) {
    pa[0] = (short)f2bf(1.0f);
    pa[1] = (short)f2bf((float)(1 + lr));
    pb[0] = (short)f2bf((float)(128 * (1 + lr)));
    pb[1] = (short)f2bf(1.0f);
  }
  f32x4 acc;
#pragma unroll
  for (int j = 0; j < 4; ++j) acc[j] = 0.f;
  MFMA16(acc, pa, pb);
#pragma unroll
  for (int r = 0; r < 4; ++r) {
    const int v = (int)acc[r];
    cm[r] = (v & 127) - 1;
    cn[r] = (v >> 7) - 1;
  }
}

__global__ void zero_f32_kernel(float* __restrict__ p, int n) {
  int i = blockIdx.x * 256 + threadIdx.x;
  if (i < n) p[i] = 0.f;
}

// prep: transpose W1, W2 to bf16; zero pad columns of the 3 bf16 p-panels
__global__ void prep_kernel(const float* __restrict__ W1, const float* __restrict__ W2,
                            unsigned short* __restrict__ W1T, unsigned short* __restrict__ W2T,
                            unsigned short* __restrict__ HT, unsigned short* __restrict__ pA,
                            unsigned short* __restrict__ pB) {
  const int idx = blockIdx.x * 256 + threadIdx.x;
  if (idx < FEAT * HID) {
    const int k = idx / HID, c = idx % HID;
    W1T[(size_t)c * FEAT + k] = f2bf(W1[idx]);
  }
  if (idx < HID * NCLS) {
    const int k = idx / NCLS, c = idx % NCLS;
    W2T[(size_t)c * HID + k] = f2bf(W2[idx]);
  }
  if (idx < 3 * 64 * (STRD - NN)) {
    const int span = 64 * (STRD - NN);
    const int p = idx / span;
    const int rem = idx % span;
    const int c = rem / (STRD - NN);
    const int col = NN + rem % (STRD - NN);
    unsigned short* pan = (p == 0) ? HT : ((p == 1) ? pA : pB);
    pan[(size_t)c * STRD + col] = 0;
  }
}

// ---------------- adj f32 -> adjb bf16 (streaming convert, pads zeroed) ----------------
__global__ __launch_bounds__(256) void cvt_adj_kernel(const float* __restrict__ adj,
                                                      unsigned short* __restrict__ adjb) {
  const int row = blockIdx.x;
  const float* src = adj + (size_t)row * NN;
  unsigned short* dst = adjb + (size_t)row * STRD;
  const int tid = threadIdx.x;
  for (int c = tid * 8; c < NN; c += 2048) {
    const float4 fa = *(const float4*)(src + c);
    const float4 fb = *(const float4*)(src + c + 4);
    s16x8 r;
    r[0] = (short)f2bf(fa.x); r[1] = (short)f2bf(fa.y);
    r[2] = (short)f2bf(fa.z); r[3] = (short)f2bf(fa.w);
    r[4] = (short)f2bf(fb.x); r[5] = (short)f2bf(fb.y);
    r[6] = (short)f2bf(fb.z); r[7] = (short)f2bf(fb.w);
    *(s16x8*)(dst + c) = r;
  }
  for (int c = NN + tid; c < STRD; c += 256) dst[c] = 0;
}

// ---------------- MLP layer 1 ----------------
__global__ __launch_bounds__(256) void mlp1_kernel(
    const float* __restrict__ X, const unsigned short* __restrict__ W1T,
    const float* __restrict__ b1, unsigned short* __restrict__ H1) {
  __shared__ float red[4][16][HID];
  const int tid = threadIdx.x, wv = tid >> 6, lane = tid & 63;
  const int lr = lane & 15, lg = lane >> 4;
  const int r0 = blockIdx.x * 16;
  int cm[4], cn[4];
  calib_mn(lane, cm, cn);

  f32x4 acc[8];
#pragma unroll
  for (int t = 0; t < 8; ++t)
#pragma unroll
    for (int j = 0; j < 4; ++j) acc[t][j] = 0.f;

  for (int s = wv * 16; s < wv * 16 + 16; ++s) {
    const int kg = s * 32 + 8 * lg;
    const float* px = X + (size_t)(r0 + lr) * FEAT + kg;
    const float4 xa = *(const float4*)(px);
    const float4 xb = *(const float4*)(px + 4);
    s16x8 af;
    af[0] = (short)f2bf(xa.x); af[1] = (short)f2bf(xa.y);
    af[2] = (short)f2bf(xa.z); af[3] = (short)f2bf(xa.w);
    af[4] = (short)f2bf(xb.x); af[5] = (short)f2bf(xb.y);
    af[6] = (short)f2bf(xb.z); af[7] = (short)f2bf(xb.w);
#pragma unroll
    for (int t = 0; t < 8; ++t) {
      const s16x8 bf = *(const s16x8*)(W1T + (size_t)(16 * t + lr) * FEAT + kg);
      MFMA16(acc[t], af, bf);
    }
  }
#pragma unroll
  for (int t = 0; t < 8; ++t)
#pragma unroll
    for (int r = 0; r < 4; ++r)
      red[wv][cm[r]][16 * t + cn[r]] = acc[t][r];
  __syncthreads();

  const int row = tid >> 4;
  const int c0 = (tid & 15) * 8;
  s16x8 hv;
#pragma unroll
  for (int j = 0; j < 8; ++j) {
    float v = red[0][row][c0 + j] + red[1][row][c0 + j] +
              red[2][row][c0 + j] + red[3][row][c0 + j] + b1[c0 + j];
    v = fmaxf(v, 0.f);
    hv[j] = (short)f2bf(v);
  }
  *(s16x8*)(H1 + (size_t)(r0 + row) * HID + c0) = hv;
}

// ---------------- MLP layer 2 -> HT (bf16 64 x STRD) + out init ----------------
__global__ __launch_bounds__(256) void mlp2_kernel(
    const unsigned short* __restrict__ H1, const unsigned short* __restrict__ W2T,
    const float* __restrict__ b2, const float* __restrict__ comb,
    unsigned short* __restrict__ HT, float* __restrict__ out) {
  __shared__ float red[4][16][NCLS];
  const int tid = threadIdx.x, wv = tid >> 6, lane = tid & 63;
  const int lr = lane & 15, lg = lane >> 4;
  const int r0 = blockIdx.x * 16;
  int cm[4], cn[4];
  calib_mn(lane, cm, cn);

  f32x4 acc[4];
#pragma unroll
  for (int t = 0; t < 4; ++t)
#pragma unroll
    for (int j = 0; j < 4; ++j) acc[t][j] = 0.f;

  const int kg = wv * 32 + 8 * lg;
  const s16x8 af = *(const s16x8*)(H1 + (size_t)(r0 + lr) * HID + kg);
#pragma unroll
  for (int t = 0; t < 4; ++t) {
    const s16x8 bf = *(const s16x8*)(W2T + (size_t)(16 * t + lr) * HID + kg);
    MFMA16(acc[t], af, bf);
  }
#pragma unroll
  for (int t = 0; t < 4; ++t)
#pragma unroll
    for (int r = 0; r < 4; ++r)
      red[wv][cm[r]][16 * t + cn[r]] = acc[t][r];
  __syncthreads();

  const int row = tid >> 4;
  const int c4 = (tid & 15) * 4;
#pragma unroll
  for (int j = 0; j < 4; ++j) {
    const int c = c4 + j;
    const float v = red[0][row][c] + red[1][row][c] + red[2][row][c] + red[3][row][c] + b2[c];
    out[(size_t)(r0 + row) * NCLS + c] = comb[2 * NCLS + c] * v;
    HT[(size_t)c * STRD + r0 + row] = f2bf(v);
  }
}

// Pipeline fence helpers (rule #18 / m152 discipline)
#define FENCE_ANCHOR() do { asm volatile("" ::: "memory"); __builtin_amdgcn_sched_barrier(0); } while (0)

// ================ gmm3: bf16 power pass — full-K, counted-vmcnt 3-deep pipeline ================
// grid(313): block owns rows r0..r0+31 exclusively, K-steps of 64, fused epilogue (out+PT).
// LDS/buf 12KB: A 32x64 bf16 (4KB, 8-slot row-rotated) + B 64x64 bf16 (8KB, rotated).
// Per wave per stage: exactly 3 global_load_lds -> steady-state vmcnt(6).
__global__ __launch_bounds__(256) void gmm3_kernel(
    const unsigned short* __restrict__ Ab, const unsigned short* __restrict__ BT,
    const float* __restrict__ comb, int didx,
    unsigned short* __restrict__ PT, float* __restrict__ out) {
  __shared__ unsigned char lds[3 * 12288];
  const int tid = threadIdx.x, wv = tid >> 6, lane = tid & 63;
  const int lr = lane & 15, lg = lane >> 4;
  const int r0 = blockIdx.x * 32;
  int cm[4], cn[4];
  calib_mn(lane, cm, cn);

  f32x4 acc[2];
#pragma unroll
  for (int rt = 0; rt < 2; ++rt)
#pragma unroll
    for (int j = 0; j < 4; ++j) acc[rt][j] = 0.f;

  auto stage = [&](int b, int s) {
    const int k0 = s * 64;
#pragma unroll
    for (int j = 0; j < 3; ++j) {
      const int g = wv * 3 + j;  // wave-uniform
      const unsigned short* src;
      if (g < 4) {  // A: units 0..255 (row=U>>3, slot=U&7)
        const int U = g * 64 + lane;
        const int row = U >> 3, ps = U & 7;
        const int gr = (r0 + row < NN) ? (r0 + row) : (NN - 1);
        src = Ab + (size_t)gr * STRD + k0 + (((ps - row) & 7) << 3);
      } else {      // B: units 256..767 (col=V>>3, slot=V&7)
        const int V = g * 64 + lane - 256;
        const int col = V >> 3, ps = V & 7;
        src = BT + (size_t)col * STRD + k0 + (((ps - col) & 7) << 3);
      }
      __builtin_amdgcn_global_load_lds(src, (void*)&lds[b * 12288 + g * 1024], 16, 0, 0);
    }
  };

  auto compute = [&](int b) {
    const unsigned char* L = &lds[b * 12288];
#pragma unroll
    for (int kk = 0; kk < 2; ++kk) {
      const int c = wv * 16 + lr;
      const s16x8 bfr =
          *(const s16x8*)(L + 4096 + c * 128 + (((kk * 4 + lg + c) & 7) << 4));
#pragma unroll
      for (int rt = 0; rt < 2; ++rt) {
        const int row = rt * 16 + lr;
        const s16x8 afr =
            *(const s16x8*)(L + row * 128 + (((kk * 4 + lg + row) & 7) << 4));
        MFMA16(acc[rt], afr, bfr);
      }
    }
  };

  stage(0, 0); stage(1, 1); stage(2, 2);
  int bi = 0;
  for (int u = 0; u < NT; ++u) {
    if (u + 2 < NT)      asm volatile("s_waitcnt vmcnt(6)" ::: "memory");
    else if (u + 1 < NT) asm volatile("s_waitcnt vmcnt(3)" ::: "memory");
    else                 asm volatile("s_waitcnt vmcnt(0)" ::: "memory");
    __builtin_amdgcn_sched_barrier(0);
    __builtin_amdgcn_s_barrier();   // all waves' tile-u DMA complete
    FENCE_ANCHOR();
    compute(bi);
    asm volatile("s_waitcnt lgkmcnt(0)" ::: "memory");  // my ds_reads complete
    __builtin_amdgcn_sched_barrier(0);
    __builtin_amdgcn_s_barrier();   // all waves done reading buf bi
    FENCE_ANCHOR();
    if (u + 3 < NT) stage(bi, u + 3);
    bi = (bi == 2) ? 0 : bi + 1;
  }

  // fused epilogue: LDS overlay transpose -> out += comb*v, PT = bf16(v^T)
  __syncthreads();
  float(*ysh)[65] = (float(*)[65])lds;
#pragma unroll
  for (int rt = 0; rt < 2; ++rt)
#pragma unroll
    for (int q = 0; q < 4; ++q)
      ysh[rt * 16 + cm[q]][wv * 16 + cn[q]] = acc[rt][q];
  __syncthreads();

#pragma unroll
  for (int j = 0; j < 2; ++j) {
    const int rr = j * 16 + (tid >> 4);
    const int c4 = (tid & 15) * 4;
    const int r = r0 + rr;
    if (r < NN) {
      const float4 cw = *(const float4*)(comb + didx * NCLS + c4);
      float4* op = (float4*)(out + (size_t)r * NCLS + c4);
      float4 ov = *op;
      ov.x += cw.x * ysh[rr][c4 + 0];
      ov.y += cw.y * ysh[rr][c4 + 1];
      ov.z += cw.z * ysh[rr][c4 + 2];
      ov.w += cw.w * ysh[rr][c4 + 3];
      *op = ov;
    }
  }
  {
    const int c = tid >> 2;
    const int rr = (tid & 3) * 8;
    if (r0 + rr + 7 < NN) {
      ushort4 u0 = make_ushort4(f2bf(ysh[rr + 0][c]), f2bf(ysh[rr + 1][c]),
                                f2bf(ysh[rr + 2][c]), f2bf(ysh[rr + 3][c]));
      ushort4 u1 = make_ushort4(f2bf(ysh[rr + 4][c]), f2bf(ysh[rr + 5][c]),
                                f2bf(ysh[rr + 6][c]), f2bf(ysh[rr + 7][c]));
      *(ushort4*)(PT + (size_t)c * STRD + r0 + rr) = u0;
      *(ushort4*)(PT + (size_t)c * STRD + r0 + rr + 4) = u1;
    }
  }
}

// ================ gmm3f: both filter passes — f32 A staged, same pipeline ================
// grid(313). LDS/buf 16KB: A 32x64 f32 (8KB, 16-slot rotated) + B 64x64 bf16 (8KB).
// 4 loads/wave/stage -> vmcnt(8/4/0). z-loop unrolled (static acc indexing, rule #20).
__global__ __launch_bounds__(256) void gmm3f_kernel(
    const float* __restrict__ A0, const float* __restrict__ A1,
    const unsigned short* __restrict__ BT, const float* __restrict__ comb,
    float* __restrict__ out) {
  __shared__ unsigned char lds[3 * 16384];
  const int tid = threadIdx.x, wv = tid >> 6, lane = tid & 63;
  const int lr = lane & 15, lg = lane >> 4;
  const int r0 = blockIdx.x * 32;
  int cm[4], cn[4];
  calib_mn(lane, cm, cn);

  f32x4 acc[2][2];
#pragma unroll
  for (int z = 0; z < 2; ++z)
#pragma unroll
    for (int rt = 0; rt < 2; ++rt)
#pragma unroll
      for (int j = 0; j < 4; ++j) acc[z][rt][j] = 0.f;

  const size_t alim = (size_t)NN * NN - 4;

  auto stagef = [&](const float* A, int b, int s) {
    const int k0 = s * 64;
#pragma unroll
    for (int j = 0; j < 4; ++j) {
      const int g = wv * 4 + j;  // wave-uniform
      if (g < 8) {  // A f32: units 0..511 (row=U>>4, slot=U&15)
        const int U = g * 64 + lane;
        const int row = U >> 4, ps = U & 15;
        const int gr = (r0 + row < NN) ? (r0 + row) : (NN - 1);
        size_t off = (size_t)gr * NN + k0 + (((ps - row) & 15) << 2);
        if (off > alim) off = alim;  // k-pad clamp; B pad zeros kill the product
        __builtin_amdgcn_global_load_lds(A + off, (void*)&lds[b * 16384 + g * 1024], 16, 0, 0);
      } else {      // B bf16: units 0..511 (col=V>>3, slot=V&7)
        const int V = (g - 8) * 64 + lane;
        const int col = V >> 3, ps = V & 7;
        const unsigned short* src = BT + (size_t)col * STRD + k0 + (((ps - col) & 7) << 3);
        __builtin_amdgcn_global_load_lds(src, (void*)&lds[b * 16384 + g * 1024], 16, 0, 0);
      }
    }
  };

#pragma unroll
  for (int z = 0; z < 2; ++z) {
    const float* A = z ? A1 : A0;
    stagef(A, 0, 0); stagef(A, 1, 1); stagef(A, 2, 2);
    int bi = 0;
    for (int u = 0; u < NT; ++u) {
      if (u + 2 < NT)      asm volatile("s_waitcnt vmcnt(8)" ::: "memory");
      else if (u + 1 < NT) asm volatile("s_waitcnt vmcnt(4)" ::: "memory");
      else                 asm volatile("s_waitcnt vmcnt(0)" ::: "memory");
      __builtin_amdgcn_sched_barrier(0);
      __builtin_amdgcn_s_barrier();
      FENCE_ANCHOR();
      {
        const unsigned char* L = &lds[bi * 16384];
#pragma unroll
        for (int kk = 0; kk < 2; ++kk) {
          const int c = wv * 16 + lr;
          const s16x8 bfr =
              *(const s16x8*)(L + 8192 + c * 128 + (((kk * 4 + lg + c) & 7) << 4));
#pragma unroll
          for (int rt = 0; rt < 2; ++rt) {
            const int row = rt * 16 + lr;
            s16x8 afr;
#pragma unroll
            for (int d = 0; d < 2; ++d) {
              const int ks = kk * 8 + lg * 2 + d;
              const float4 f =
                  *(const float4*)(L + row * 256 + (((ks + row) & 15) << 4));
              afr[4 * d + 0] = (short)f2bf(f.x);
              afr[4 * d + 1] = (short)f2bf(f.y);
              afr[4 * d + 2] = (short)f2bf(f.z);
              afr[4 * d + 3] = (short)f2bf(f.w);
            }
            MFMA16(acc[z][rt], afr, bfr);
          }
        }
      }
      asm volatile("s_waitcnt lgkmcnt(0)" ::: "memory");
      __builtin_amdgcn_sched_barrier(0);
      __builtin_amdgcn_s_barrier();
      FENCE_ANCHOR();
      if (u + 3 < NT) stagef(A, bi, u + 3);
      bi = (bi == 2) ? 0 : bi + 1;
    }
  }

  // fused epilogue: out += c0*v0 + c1*v1 (rows exclusive, non-atomic)
  __syncthreads();
  float(*ysh)[65] = (float(*)[65])lds;
#pragma unroll
  for (int rt = 0; rt < 2; ++rt)
#pragma unroll
    for (int q = 0; q < 4; ++q) {
      const int col = wv * 16 + cn[q];
      ysh[rt * 16 + cm[q]][col] =
          comb[col] * acc[0][rt][q] + comb[NCLS + col] * acc[1][rt][q];
    }
  __syncthreads();
#pragma unroll
  for (int j = 0; j < 2; ++j) {
    const int rr = j * 16 + (tid >> 4);
    const int c4 = (tid & 15) * 4;
    const int r = r0 + rr;
    if (r < NN) {
      float4* op = (float4*)(out + (size_t)r * NCLS + c4);
      float4 ov = *op;
      ov.x += ysh[rr][c4 + 0];
      ov.y += ysh[rr][c4 + 1];
      ov.z += ysh[rr][c4 + 2];
      ov.w += ysh[rr][c4 + 3];
      *op = ov;
    }
  }
}

extern "C" void kernel_launch(void* const* d_in, const int* in_sizes, int n_in,
                              void* d_out, int out_size, void* d_ws, size_t ws_size,
                              hipStream_t stream) {
  const float* x = (const float*)d_in[0];
  const float* adj = (const float*)d_in[1];
  const float* filt0 = (const float*)d_in[2];
  const float* filt1 = (const float*)d_in[3];
  const float* W1 = (const float*)d_in[4];
  const float* b1 = (const float*)d_in[5];
  const float* W2 = (const float*)d_in[6];
  const float* b2 = (const float*)d_in[7];
  const float* comb = (const float*)d_in[8];
  float* out = (float*)d_out;

  unsigned char* wsb = (unsigned char*)d_ws;
  size_t off = 0;
  auto carve = [&](size_t bytes) -> void* {
    void* p = wsb + off;
    off += (bytes + 255) & ~(size_t)255;
    return p;
  };
  unsigned short* W1T = (unsigned short*)carve((size_t)FEAT * HID * 2);
  unsigned short* W2T = (unsigned short*)carve((size_t)HID * NCLS * 2);
  unsigned short* H1 = (unsigned short*)carve((size_t)NN * HID * 2);
  unsigned short* HT = (unsigned short*)carve((size_t)NCLS * STRD * 2);
  unsigned short* pA = (unsigned short*)carve((size_t)NCLS * STRD * 2);
  unsigned short* pB = (unsigned short*)carve((size_t)NCLS * STRD * 2);
  unsigned short* adjb = (unsigned short*)carve((size_t)NN * STRD * 2);

  if (ws_size < off) {
    // Sentinel: absmax == 5.40625 exactly => ws too small.
    zero_f32_kernel<<<(out_size + 255) / 256, 256, 0, stream>>>(out, out_size);
    return;
  }

  prep_kernel<<<(FEAT * HID + 255) / 256, 256, 0, stream>>>(W1, W2, W1T, W2T, HT, pA, pB);
  mlp1_kernel<<<(NN + 15) / 16, 256, 0, stream>>>(x, W1T, b1, H1);
  mlp2_kernel<<<(NN + 15) / 16, 256, 0, stream>>>(H1, W2T, b2, comb, HT, out);
  cvt_adj_kernel<<<NN, 256, 0, stream>>>(adj, adjb);

  gmm3f_kernel<<<313, 256, 0, stream>>>(filt0, filt1, HT, comb, out);

  const unsigned short* pin = HT;
  for (int k = 1; k <= 10; ++k) {
    unsigned short* pout = (k & 1) ? pA : pB;
    gmm3_kernel<<<313, 256, 0, stream>>>(adjb, pin, comb, 2 + k, pout, out);
    pin = pout;
  }
}

// Round 10
// 1044.178 us; speedup vs baseline: 1.1518x; 1.1518x over previous
//
#include <hip/hip_runtime.h>

#define NN 10000
#define STRD 10272  // bf16 panel/adjb row stride (elements)
#define KSPLIT 16   // K-slices
#define VSTEPS 20   // K-steps of 32 per block (16*20*32 = 10240 padded cols)
#define FEAT 2048
#define HID 128
#define NCLS 64

typedef short s16x8 __attribute__((ext_vector_type(8)));
typedef float f32x4 __attribute__((ext_vector_type(4)));

static __device__ __forceinline__ unsigned short f2bf(float f) {
  unsigned int u = __float_as_uint(f);
  u += 0x7FFFu + ((u >> 16) & 1u);
  return (unsigned short)(u >> 16);
}

#define MFMA16(accv, av, bv) \
  (accv) = __builtin_amdgcn_mfma_f32_16x16x32_bf16((av), (bv), (accv), 0, 0, 0)

// Self-calibration of the MFMA C/D lane->(m,n) mapping (proved correct in R2).
__device__ __forceinline__ void calib_mn(int lane, int* cm, int* cn) {
  const int lr = lane & 15;
  const int lg = lane >> 4;
  s16x8 pa, pb;
#pragma unroll
  for (int j = 0; j < 8; ++j) { pa[j] = 0; pb[j] = 0; }
  if (lg == 0) {
    pa[0] = (short)f2bf(1.0f);
    pa[1] = (short)f2bf((float)(1 + lr));
    pb[0] = (short)f2bf((float)(128 * (1 + lr)));
    pb[1] = (short)f2bf(1.0f);
  }
  f32x4 acc;
#pragma unroll
  for (int j = 0; j < 4; ++j) acc[j] = 0.f;
  MFMA16(acc, pa, pb);
#pragma unroll
  for (int r = 0; r < 4; ++r) {
    const int v = (int)acc[r];
    cm[r] = (v & 127) - 1;
    cn[r] = (v >> 7) - 1;
  }
}

__global__ void zero_f32_kernel(float* __restrict__ p, int n) {
  int i = blockIdx.x * 256 + threadIdx.x;
  if (i < n) p[i] = 0.f;
}

// prep: transpose W1, W2 to bf16; zero pad columns of the 3 bf16 p-panels
__global__ void prep_kernel(const float* __restrict__ W1, const float* __restrict__ W2,
                            unsigned short* __restrict__ W1T, unsigned short* __restrict__ W2T,
                            unsigned short* __restrict__ HT, unsigned short* __restrict__ pA,
                            unsigned short* __restrict__ pB) {
  const int idx = blockIdx.x * 256 + threadIdx.x;
  if (idx < FEAT * HID) {
    const int k = idx / HID, c = idx % HID;
    W1T[(size_t)c * FEAT + k] = f2bf(W1[idx]);
  }
  if (idx < HID * NCLS) {
    const int k = idx / NCLS, c = idx % NCLS;
    W2T[(size_t)c * HID + k] = f2bf(W2[idx]);
  }
  if (idx < 3 * 64 * (STRD - NN)) {
    const int span = 64 * (STRD - NN);
    const int p = idx / span;
    const int rem = idx % span;
    const int c = rem / (STRD - NN);
    const int col = NN + rem % (STRD - NN);
    unsigned short* pan = (p == 0) ? HT : ((p == 1) ? pA : pB);
    pan[(size_t)c * STRD + col] = 0;
  }
}

// ---------------- adj f32 -> adjb bf16 (streaming convert, pads zeroed) ----------------
__global__ __launch_bounds__(256) void cvt_adj_kernel(const float* __restrict__ adj,
                                                      unsigned short* __restrict__ adjb) {
  const int row = blockIdx.x;
  const float* src = adj + (size_t)row * NN;
  unsigned short* dst = adjb + (size_t)row * STRD;
  const int tid = threadIdx.x;
  for (int c = tid * 8; c < NN; c += 2048) {
    const float4 fa = *(const float4*)(src + c);
    const float4 fb = *(const float4*)(src + c + 4);
    s16x8 r;
    r[0] = (short)f2bf(fa.x); r[1] = (short)f2bf(fa.y);
    r[2] = (short)f2bf(fa.z); r[3] = (short)f2bf(fa.w);
    r[4] = (short)f2bf(fb.x); r[5] = (short)f2bf(fb.y);
    r[6] = (short)f2bf(fb.z); r[7] = (short)f2bf(fb.w);
    *(s16x8*)(dst + c) = r;
  }
  for (int c = NN + tid; c < STRD; c += 256) dst[c] = 0;
}

// ---------------- MLP layer 1 ----------------
__global__ __launch_bounds__(256) void mlp1_kernel(
    const float* __restrict__ X, const unsigned short* __restrict__ W1T,
    const float* __restrict__ b1, unsigned short* __restrict__ H1) {
  __shared__ float red[4][16][HID];
  const int tid = threadIdx.x, wv = tid >> 6, lane = tid & 63;
  const int lr = lane & 15, lg = lane >> 4;
  const int r0 = blockIdx.x * 16;
  int cm[4], cn[4];
  calib_mn(lane, cm, cn);

  f32x4 acc[8];
#pragma unroll
  for (int t = 0; t < 8; ++t)
#pragma unroll
    for (int j = 0; j < 4; ++j) acc[t][j] = 0.f;

  for (int s = wv * 16; s < wv * 16 + 16; ++s) {
    const int kg = s * 32 + 8 * lg;
    const float* px = X + (size_t)(r0 + lr) * FEAT + kg;
    const float4 xa = *(const float4*)(px);
    const float4 xb = *(const float4*)(px + 4);
    s16x8 af;
    af[0] = (short)f2bf(xa.x); af[1] = (short)f2bf(xa.y);
    af[2] = (short)f2bf(xa.z); af[3] = (short)f2bf(xa.w);
    af[4] = (short)f2bf(xb.x); af[5] = (short)f2bf(xb.y);
    af[6] = (short)f2bf(xb.z); af[7] = (short)f2bf(xb.w);
#pragma unroll
    for (int t = 0; t < 8; ++t) {
      const s16x8 bf = *(const s16x8*)(W1T + (size_t)(16 * t + lr) * FEAT + kg);
      MFMA16(acc[t], af, bf);
    }
  }
#pragma unroll
  for (int t = 0; t < 8; ++t)
#pragma unroll
    for (int r = 0; r < 4; ++r)
      red[wv][cm[r]][16 * t + cn[r]] = acc[t][r];
  __syncthreads();

  const int row = tid >> 4;
  const int c0 = (tid & 15) * 8;
  s16x8 hv;
#pragma unroll
  for (int j = 0; j < 8; ++j) {
    float v = red[0][row][c0 + j] + red[1][row][c0 + j] +
              red[2][row][c0 + j] + red[3][row][c0 + j] + b1[c0 + j];
    v = fmaxf(v, 0.f);
    hv[j] = (short)f2bf(v);
  }
  *(s16x8*)(H1 + (size_t)(r0 + row) * HID + c0) = hv;
}

// ---------------- MLP layer 2 -> HT (bf16 64 x STRD) + out init ----------------
__global__ __launch_bounds__(256) void mlp2_kernel(
    const unsigned short* __restrict__ H1, const unsigned short* __restrict__ W2T,
    const float* __restrict__ b2, const float* __restrict__ comb,
    unsigned short* __restrict__ HT, float* __restrict__ out) {
  __shared__ float red[4][16][NCLS];
  const int tid = threadIdx.x, wv = tid >> 6, lane = tid & 63;
  const int lr = lane & 15, lg = lane >> 4;
  const int r0 = blockIdx.x * 16;
  int cm[4], cn[4];
  calib_mn(lane, cm, cn);

  f32x4 acc[4];
#pragma unroll
  for (int t = 0; t < 4; ++t)
#pragma unroll
    for (int j = 0; j < 4; ++j) acc[t][j] = 0.f;

  const int kg = wv * 32 + 8 * lg;
  const s16x8 af = *(const s16x8*)(H1 + (size_t)(r0 + lr) * HID + kg);
#pragma unroll
  for (int t = 0; t < 4; ++t) {
    const s16x8 bf = *(const s16x8*)(W2T + (size_t)(16 * t + lr) * HID + kg);
    MFMA16(acc[t], af, bf);
  }
#pragma unroll
  for (int t = 0; t < 4; ++t)
#pragma unroll
    for (int r = 0; r < 4; ++r)
      red[wv][cm[r]][16 * t + cn[r]] = acc[t][r];
  __syncthreads();

  const int row = tid >> 4;
  const int c4 = (tid & 15) * 4;
#pragma unroll
  for (int j = 0; j < 4; ++j) {
    const int c = c4 + j;
    const float v = red[0][row][c] + red[1][row][c] + red[2][row][c] + red[3][row][c] + b2[c];
    out[(size_t)(r0 + row) * NCLS + c] = comb[2 * NCLS + c] * v;
    HT[(size_t)c * STRD + r0 + row] = f2bf(v);
  }
}

// ================ gmm2: bf16 power pass — M=64, K-split, 2-buf DMA pipeline ================
// grid (157, 16): x = 64-row M-tile, y = K-slice (20 steps of K=32).
// LDS/buf 8KB: A 64x32 bf16 (4KB) + B 64x32 bf16 (4KB), XOR-swizzled via global source.
// 2 global_load_lds per thread per stage. Epilogue: atomicAdd into Yf.
__global__ __launch_bounds__(256) void gmm2_kernel(
    const unsigned short* __restrict__ Ab,  // adjb (STRD stride)
    const unsigned short* __restrict__ BT,  // 64 x STRD bf16 (p transposed)
    float* __restrict__ Yf) {
  __shared__ unsigned char lds[2][8192];  // [buf][A:0..4095 | B:4096..8191]
  const int tid = threadIdx.x, wv = tid >> 6, lane = tid & 63;
  const int lr = lane & 15, lg = lane >> 4;
  const int r0 = blockIdx.x * 64;
  const int s0 = blockIdx.y * VSTEPS;
  int cm[4], cn[4];
  calib_mn(lane, cm, cn);

  f32x4 acc[4];
#pragma unroll
  for (int t = 0; t < 4; ++t)
#pragma unroll
    for (int j = 0; j < 4; ++j) acc[t][j] = 0.f;

  auto stage = [&](int b, int s) {
    const int k0 = s * 32;
    {  // A: 256 units of 16B (4/row), row = U>>2, chunk = slot ^ (row&3)
      const int U = wv * 64 + lane;
      const int row = U >> 2, slot = U & 3;
      const int chunk = slot ^ (row & 3);
      const int gr = (r0 + row < NN) ? (r0 + row) : (NN - 1);
      __builtin_amdgcn_global_load_lds(Ab + (size_t)gr * STRD + k0 + chunk * 8,
                                       (void*)&lds[b][wv * 1024], 16, 0, 0);
    }
    {  // B: 256 units (4/col), col = V>>2, chunk = slot ^ (col&3)
      const int V = wv * 64 + lane;
      const int col = V >> 2, slot = V & 3;
      const int chunk = slot ^ (col & 3);
      __builtin_amdgcn_global_load_lds(BT + (size_t)col * STRD + k0 + chunk * 8,
                                       (void*)&lds[b][4096 + wv * 1024], 16, 0, 0);
    }
  };

  stage(0, s0);
  __syncthreads();

  int cur = 0;
  for (int u = 0; u < VSTEPS; ++u) {
    if (u + 1 < VSTEPS) stage(cur ^ 1, s0 + u + 1);  // issue next tile, overlaps compute
    const unsigned char* L = lds[cur];
    const int row = wv * 16 + lr;
    const s16x8 af = *(const s16x8*)(L + row * 64 + ((lg ^ (row & 3)) << 4));
#pragma unroll
    for (int t = 0; t < 4; ++t) {
      const int col = t * 16 + lr;
      const s16x8 bf = *(const s16x8*)(L + 4096 + col * 64 + ((lg ^ (col & 3)) << 4));
      MFMA16(acc[t], af, bf);
    }
    __syncthreads();  // next buffer's DMA landed (had compute-phase to cover latency)
    cur ^= 1;
  }

#pragma unroll
  for (int t = 0; t < 4; ++t) {
#pragma unroll
    for (int q = 0; q < 4; ++q) {
      const int c = 16 * t + cn[q];
      const int r = r0 + wv * 16 + cm[q];
      if (r < NN) atomicAdd(&Yf[(size_t)r * NCLS + c], acc[t][q]);
    }
  }
}

// ================ gmmf: filter pass — M=64, f32 A staged via DMA, 2-buf ================
// grid (157, 16, 2): z = filter. LDS/buf 12KB: A 64x32 f32 (8KB, XOR 8-slot) + B 4KB.
// 3 global_load_lds per thread per stage. A-source clamped; B pad zeros kill k>=NN terms.
__global__ __launch_bounds__(256) void gmmf_kernel(
    const float* __restrict__ A0, const float* __restrict__ A1,
    const unsigned short* __restrict__ BT, float* __restrict__ out,
    const float* __restrict__ comb) {
  __shared__ unsigned char lds[2][12288];  // [buf][A:0..8191 | B:8192..12287]
  const int tid = threadIdx.x, wv = tid >> 6, lane = tid & 63;
  const int lr = lane & 15, lg = lane >> 4;
  const int r0 = blockIdx.x * 64;
  const int s0 = blockIdx.y * VSTEPS;
  const int z = blockIdx.z;
  const float* A = z ? A1 : A0;
  int cm[4], cn[4];
  calib_mn(lane, cm, cn);

  f32x4 acc[4];
#pragma unroll
  for (int t = 0; t < 4; ++t)
#pragma unroll
    for (int j = 0; j < 4; ++j) acc[t][j] = 0.f;

  const size_t alim = (size_t)NN * NN - 4;

  auto stage = [&](int b, int s) {
    const int k0 = s * 32;
#pragma unroll
    for (int i = 0; i < 2; ++i) {  // A f32: 512 units (8/row), row = U>>3, chunk = slot ^ (row&7)
      const int U = i * 256 + wv * 64 + lane;
      const int row = U >> 3, slot = U & 7;
      const int chunk = slot ^ (row & 7);
      const int gr = (r0 + row < NN) ? (r0 + row) : (NN - 1);
      size_t off = (size_t)gr * NN + k0 + chunk * 4;
      if (off > alim) off = alim;  // k-pad clamp; B zeros kill the product
      __builtin_amdgcn_global_load_lds(A + off,
                                       (void*)&lds[b][(i * 256 + wv * 64) * 16], 16, 0, 0);
    }
    {  // B bf16: 256 units (4/col)
      const int V = wv * 64 + lane;
      const int col = V >> 2, slot = V & 3;
      const int chunk = slot ^ (col & 3);
      __builtin_amdgcn_global_load_lds(BT + (size_t)col * STRD + k0 + chunk * 8,
                                       (void*)&lds[b][8192 + wv * 1024], 16, 0, 0);
    }
  };

  stage(0, s0);
  __syncthreads();

  int cur = 0;
  for (int u = 0; u < VSTEPS; ++u) {
    if (u + 1 < VSTEPS) stage(cur ^ 1, s0 + u + 1);
    const unsigned char* L = lds[cur];
    const int row = wv * 16 + lr;
    s16x8 af;
#pragma unroll
    for (int d = 0; d < 2; ++d) {
      const int c = 2 * lg + d;
      const float4 f = *(const float4*)(L + row * 128 + ((c ^ (row & 7)) << 4));
      af[4 * d + 0] = (short)f2bf(f.x);
      af[4 * d + 1] = (short)f2bf(f.y);
      af[4 * d + 2] = (short)f2bf(f.z);
      af[4 * d + 3] = (short)f2bf(f.w);
    }
#pragma unroll
    for (int t = 0; t < 4; ++t) {
      const int col = t * 16 + lr;
      const s16x8 bf = *(const s16x8*)(L + 8192 + col * 64 + ((lg ^ (col & 3)) << 4));
      MFMA16(acc[t], af, bf);
    }
    __syncthreads();
    cur ^= 1;
  }

#pragma unroll
  for (int t = 0; t < 4; ++t) {
#pragma unroll
    for (int q = 0; q < 4; ++q) {
      const int c = 16 * t + cn[q];
      const int r = r0 + wv * 16 + cm[q];
      if (r < NN) atomicAdd(&out[(size_t)r * NCLS + c], comb[z * NCLS + c] * acc[t][q]);
    }
  }
}

// ---------------- finish: out += comb*Yf, PT = bf16(Yf^T), Yf = 0 ----------------
__global__ __launch_bounds__(256) void finish_old_kernel(
    float* __restrict__ Yf, const float* __restrict__ comb, int didx,
    unsigned short* __restrict__ PT, float* __restrict__ out) {
  __shared__ float ysh[32][65];
  const int tid = threadIdx.x;
  const int r0 = blockIdx.x * 32;
#pragma unroll
  for (int j = 0; j < 8; ++j) {
    const int idx = j * 256 + tid;
    const int rr = idx >> 6;
    const int c = idx & 63;
    const int r = r0 + rr;
    if (r < NN) {
      const float y = Yf[(size_t)r * NCLS + c];
      Yf[(size_t)r * NCLS + c] = 0.f;
      ysh[rr][c] = y;
      out[(size_t)r * NCLS + c] += comb[didx * NCLS + c] * y;
    }
  }
  __syncthreads();
  const int c = tid >> 2;
  const int rr = (tid & 3) * 8;
  if (r0 + rr + 7 < NN) {
    ushort4 u0 = make_ushort4(f2bf(ysh[rr + 0][c]), f2bf(ysh[rr + 1][c]),
                              f2bf(ysh[rr + 2][c]), f2bf(ysh[rr + 3][c]));
    ushort4 u1 = make_ushort4(f2bf(ysh[rr + 4][c]), f2bf(ysh[rr + 5][c]),
                              f2bf(ysh[rr + 6][c]), f2bf(ysh[rr + 7][c]));
    *(ushort4*)(PT + (size_t)c * STRD + r0 + rr) = u0;
    *(ushort4*)(PT + (size_t)c * STRD + r0 + rr + 4) = u1;
  }
}

extern "C" void kernel_launch(void* const* d_in, const int* in_sizes, int n_in,
                              void* d_out, int out_size, void* d_ws, size_t ws_size,
                              hipStream_t stream) {
  const float* x = (const float*)d_in[0];
  const float* adj = (const float*)d_in[1];
  const float* filt0 = (const float*)d_in[2];
  const float* filt1 = (const float*)d_in[3];
  const float* W1 = (const float*)d_in[4];
  const float* b1 = (const float*)d_in[5];
  const float* W2 = (const float*)d_in[6];
  const float* b2 = (const float*)d_in[7];
  const float* comb = (const float*)d_in[8];
  float* out = (float*)d_out;

  unsigned char* wsb = (unsigned char*)d_ws;
  size_t off = 0;
  auto carve = [&](size_t bytes) -> void* {
    void* p = wsb + off;
    off += (bytes + 255) & ~(size_t)255;
    return p;
  };
  unsigned short* W1T = (unsigned short*)carve((size_t)FEAT * HID * 2);
  unsigned short* W2T = (unsigned short*)carve((size_t)HID * NCLS * 2);
  unsigned short* H1 = (unsigned short*)carve((size_t)NN * HID * 2);
  float* Yf = (float*)carve((size_t)NN * NCLS * 4);
  unsigned short* HT = (unsigned short*)carve((size_t)NCLS * STRD * 2);
  unsigned short* pA = (unsigned short*)carve((size_t)NCLS * STRD * 2);
  unsigned short* pB = (unsigned short*)carve((size_t)NCLS * STRD * 2);
  unsigned short* adjb = (unsigned short*)carve((size_t)NN * STRD * 2);

  if (ws_size < off) {
    // Sentinel: absmax == 5.40625 exactly => ws too small.
    zero_f32_kernel<<<(out_size + 255) / 256, 256, 0, stream>>>(out, out_size);
    return;
  }

  zero_f32_kernel<<<(NN * NCLS + 255) / 256, 256, 0, stream>>>(Yf, NN * NCLS);
  prep_kernel<<<(FEAT * HID + 255) / 256, 256, 0, stream>>>(W1, W2, W1T, W2T, HT, pA, pB);
  mlp1_kernel<<<(NN + 15) / 16, 256, 0, stream>>>(x, W1T, b1, H1);
  mlp2_kernel<<<(NN + 15) / 16, 256, 0, stream>>>(H1, W2T, b2, comb, HT, out);
  cvt_adj_kernel<<<NN, 256, 0, stream>>>(adj, adjb);

  // filters (f32-staged, scaled atomics into out)
  gmmf_kernel<<<dim3(157, KSPLIT, 2), 256, 0, stream>>>(filt0, filt1, HT, out, comb);

  const unsigned short* pin = HT;
  for (int k = 1; k <= 10; ++k) {
    unsigned short* pout = (k & 1) ? pA : pB;
    gmm2_kernel<<<dim3(157, KSPLIT), 256, 0, stream>>>(adjb, pin, Yf);
    finish_old_kernel<<<313, 256, 0, stream>>>(Yf, comb, 2 + k, pout, out);
    pin = pout;
  }
}

// Round 11
// 974.849 us; speedup vs baseline: 1.2337x; 1.0711x over previous
//
#include <hip/hip_runtime.h>

#define NN 10000
#define STRD 10272  // bf16 panel/adjb row stride (elements)
#define KSPLIT 16   // K-slices
#define VSTEPS 20   // K-steps of 32 per block (16*20*32 = 10240 padded cols)
#define FEAT 2048
#define HID 128
#define NCLS 64

typedef short s16x8 __attribute__((ext_vector_type(8)));
typedef float f32x4 __attribute__((ext_vector_type(4)));

static __device__ __forceinline__ unsigned short f2bf(float f) {
  unsigned int u = __float_as_uint(f);
  u += 0x7FFFu + ((u >> 16) & 1u);
  return (unsigned short)(u >> 16);
}

#define MFMA16(accv, av, bv) \
  (accv) = __builtin_amdgcn_mfma_f32_16x16x32_bf16((av), (bv), (accv), 0, 0, 0)

// Pipeline fence helpers (rule #18 / m152 discipline; proven in R9)
#define FENCE_ANCHOR() do { asm volatile("" ::: "memory"); __builtin_amdgcn_sched_barrier(0); } while (0)

// Self-calibration of the MFMA C/D lane->(m,n) mapping (proved correct in R2).
__device__ __forceinline__ void calib_mn(int lane, int* cm, int* cn) {
  const int lr = lane & 15;
  const int lg = lane >> 4;
  s16x8 pa, pb;
#pragma unroll
  for (int j = 0; j < 8; ++j) { pa[j] = 0; pb[j] = 0; }
  if (lg == 0) {
    pa[0] = (short)f2bf(1.0f);
    pa[1] = (short)f2bf((float)(1 + lr));
    pb[0] = (short)f2bf((float)(128 * (1 + lr)));
    pb[1] = (short)f2bf(1.0f);
  }
  f32x4 acc;
#pragma unroll
  for (int j = 0; j < 4; ++j) acc[j] = 0.f;
  MFMA16(acc, pa, pb);
#pragma unroll
  for (int r = 0; r < 4; ++r) {
    const int v = (int)acc[r];
    cm[r] = (v & 127) - 1;
    cn[r] = (v >> 7) - 1;
  }
}

__global__ void zero_f32_kernel(float* __restrict__ p, int n) {
  int i = blockIdx.x * 256 + threadIdx.x;
  if (i < n) p[i] = 0.f;
}

// prep: transpose W1, W2 to bf16; zero pad columns of the 3 bf16 p-panels
__global__ void prep_kernel(const float* __restrict__ W1, const float* __restrict__ W2,
                            unsigned short* __restrict__ W1T, unsigned short* __restrict__ W2T,
                            unsigned short* __restrict__ HT, unsigned short* __restrict__ pA,
                            unsigned short* __restrict__ pB) {
  const int idx = blockIdx.x * 256 + threadIdx.x;
  if (idx < FEAT * HID) {
    const int k = idx / HID, c = idx % HID;
    W1T[(size_t)c * FEAT + k] = f2bf(W1[idx]);
  }
  if (idx < HID * NCLS) {
    const int k = idx / NCLS, c = idx % NCLS;
    W2T[(size_t)c * HID + k] = f2bf(W2[idx]);
  }
  if (idx < 3 * 64 * (STRD - NN)) {
    const int span = 64 * (STRD - NN);
    const int p = idx / span;
    const int rem = idx % span;
    const int c = rem / (STRD - NN);
    const int col = NN + rem % (STRD - NN);
    unsigned short* pan = (p == 0) ? HT : ((p == 1) ? pA : pB);
    pan[(size_t)c * STRD + col] = 0;
  }
}

// ---------------- adj f32 -> adjb bf16 (streaming convert, pads zeroed) ----------------
__global__ __launch_bounds__(256) void cvt_adj_kernel(const float* __restrict__ adj,
                                                      unsigned short* __restrict__ adjb) {
  const int row = blockIdx.x;
  const float* src = adj + (size_t)row * NN;
  unsigned short* dst = adjb + (size_t)row * STRD;
  const int tid = threadIdx.x;
  for (int c = tid * 8; c < NN; c += 2048) {
    const float4 fa = *(const float4*)(src + c);
    const float4 fb = *(const float4*)(src + c + 4);
    s16x8 r;
    r[0] = (short)f2bf(fa.x); r[1] = (short)f2bf(fa.y);
    r[2] = (short)f2bf(fa.z); r[3] = (short)f2bf(fa.w);
    r[4] = (short)f2bf(fb.x); r[5] = (short)f2bf(fb.y);
    r[6] = (short)f2bf(fb.z); r[7] = (short)f2bf(fb.w);
    *(s16x8*)(dst + c) = r;
  }
  for (int c = NN + tid; c < STRD; c += 256) dst[c] = 0;
}

// ---------------- MLP layer 1 ----------------
__global__ __launch_bounds__(256) void mlp1_kernel(
    const float* __restrict__ X, const unsigned short* __restrict__ W1T,
    const float* __restrict__ b1, unsigned short* __restrict__ H1) {
  __shared__ float red[4][16][HID];
  const int tid = threadIdx.x, wv = tid >> 6, lane = tid & 63;
  const int lr = lane & 15, lg = lane >> 4;
  const int r0 = blockIdx.x * 16;
  int cm[4], cn[4];
  calib_mn(lane, cm, cn);

  f32x4 acc[8];
#pragma unroll
  for (int t = 0; t < 8; ++t)
#pragma unroll
    for (int j = 0; j < 4; ++j) acc[t][j] = 0.f;

  for (int s = wv * 16; s < wv * 16 + 16; ++s) {
    const int kg = s * 32 + 8 * lg;
    const float* px = X + (size_t)(r0 + lr) * FEAT + kg;
    const float4 xa = *(const float4*)(px);
    const float4 xb = *(const float4*)(px + 4);
    s16x8 af;
    af[0] = (short)f2bf(xa.x); af[1] = (short)f2bf(xa.y);
    af[2] = (short)f2bf(xa.z); af[3] = (short)f2bf(xa.w);
    af[4] = (short)f2bf(xb.x); af[5] = (short)f2bf(xb.y);
    af[6] = (short)f2bf(xb.z); af[7] = (short)f2bf(xb.w);
#pragma unroll
    for (int t = 0; t < 8; ++t) {
      const s16x8 bf = *(const s16x8*)(W1T + (size_t)(16 * t + lr) * FEAT + kg);
      MFMA16(acc[t], af, bf);
    }
  }
#pragma unroll
  for (int t = 0; t < 8; ++t)
#pragma unroll
    for (int r = 0; r < 4; ++r)
      red[wv][cm[r]][16 * t + cn[r]] = acc[t][r];
  __syncthreads();

  const int row = tid >> 4;
  const int c0 = (tid & 15) * 8;
  s16x8 hv;
#pragma unroll
  for (int j = 0; j < 8; ++j) {
    float v = red[0][row][c0 + j] + red[1][row][c0 + j] +
              red[2][row][c0 + j] + red[3][row][c0 + j] + b1[c0 + j];
    v = fmaxf(v, 0.f);
    hv[j] = (short)f2bf(v);
  }
  *(s16x8*)(H1 + (size_t)(r0 + row) * HID + c0) = hv;
}

// ---------------- MLP layer 2 -> HT (bf16 64 x STRD) + out init ----------------
__global__ __launch_bounds__(256) void mlp2_kernel(
    const unsigned short* __restrict__ H1, const unsigned short* __restrict__ W2T,
    const float* __restrict__ b2, const float* __restrict__ comb,
    unsigned short* __restrict__ HT, float* __restrict__ out) {
  __shared__ float red[4][16][NCLS];
  const int tid = threadIdx.x, wv = tid >> 6, lane = tid & 63;
  const int lr = lane & 15, lg = lane >> 4;
  const int r0 = blockIdx.x * 16;
  int cm[4], cn[4];
  calib_mn(lane, cm, cn);

  f32x4 acc[4];
#pragma unroll
  for (int t = 0; t < 4; ++t)
#pragma unroll
    for (int j = 0; j < 4; ++j) acc[t][j] = 0.f;

  const int kg = wv * 32 + 8 * lg;
  const s16x8 af = *(const s16x8*)(H1 + (size_t)(r0 + lr) * HID + kg);
#pragma unroll
  for (int t = 0; t < 4; ++t) {
    const s16x8 bf = *(const s16x8*)(W2T + (size_t)(16 * t + lr) * HID + kg);
    MFMA16(acc[t], af, bf);
  }
#pragma unroll
  for (int t = 0; t < 4; ++t)
#pragma unroll
    for (int r = 0; r < 4; ++r)
      red[wv][cm[r]][16 * t + cn[r]] = acc[t][r];
  __syncthreads();

  const int row = tid >> 4;
  const int c4 = (tid & 15) * 4;
#pragma unroll
  for (int j = 0; j < 4; ++j) {
    const int c = c4 + j;
    const float v = red[0][row][c] + red[1][row][c] + red[2][row][c] + red[3][row][c] + b2[c];
    out[(size_t)(r0 + row) * NCLS + c] = comb[2 * NCLS + c] * v;
    HT[(size_t)c * STRD + r0 + row] = f2bf(v);
  }
}

// ================ gmm2: bf16 power pass — M=64, K-split, 3-buf counted-vmcnt ================
// grid (157, 16). LDS 3 x 8KB (A 4KB + B 4KB per buf), XOR-swizzled via global source.
// 2 global_load_lds per wave per stage -> steady-state vmcnt(4), tail 2 -> 0.
__global__ __launch_bounds__(256) void gmm2_kernel(
    const unsigned short* __restrict__ Ab,  // adjb (STRD stride)
    const unsigned short* __restrict__ BT,  // 64 x STRD bf16 (p transposed)
    float* __restrict__ Yf) {
  __shared__ unsigned char lds[3][8192];  // [buf][A:0..4095 | B:4096..8191]
  const int tid = threadIdx.x, wv = tid >> 6, lane = tid & 63;
  const int lr = lane & 15, lg = lane >> 4;
  const int r0 = blockIdx.x * 64;
  const int s0 = blockIdx.y * VSTEPS;
  int cm[4], cn[4];
  calib_mn(lane, cm, cn);

  f32x4 acc[4];
#pragma unroll
  for (int t = 0; t < 4; ++t)
#pragma unroll
    for (int j = 0; j < 4; ++j) acc[t][j] = 0.f;

  auto stage = [&](int b, int s) {
    const int k0 = s * 32;
    {  // A: 256 units of 16B (4/row), row = U>>2, chunk = slot ^ (row&3)
      const int U = wv * 64 + lane;
      const int row = U >> 2, slot = U & 3;
      const int chunk = slot ^ (row & 3);
      const int gr = (r0 + row < NN) ? (r0 + row) : (NN - 1);
      __builtin_amdgcn_global_load_lds(Ab + (size_t)gr * STRD + k0 + chunk * 8,
                                       (void*)&lds[b][wv * 1024], 16, 0, 0);
    }
    {  // B: 256 units (4/col), col = V>>2, chunk = slot ^ (col&3)
      const int V = wv * 64 + lane;
      const int col = V >> 2, slot = V & 3;
      const int chunk = slot ^ (col & 3);
      __builtin_amdgcn_global_load_lds(BT + (size_t)col * STRD + k0 + chunk * 8,
                                       (void*)&lds[b][4096 + wv * 1024], 16, 0, 0);
    }
  };

  stage(0, s0); stage(1, s0 + 1); stage(2, s0 + 2);

  int bi = 0;
  for (int u = 0; u < VSTEPS; ++u) {
    if (u + 2 < VSTEPS)      asm volatile("s_waitcnt vmcnt(4)" ::: "memory");
    else if (u + 1 < VSTEPS) asm volatile("s_waitcnt vmcnt(2)" ::: "memory");
    else                     asm volatile("s_waitcnt vmcnt(0)" ::: "memory");
    __builtin_amdgcn_sched_barrier(0);
    __builtin_amdgcn_s_barrier();  // all waves' stage-u DMA landed
    FENCE_ANCHOR();
    {
      const unsigned char* L = lds[bi];
      const int row = wv * 16 + lr;
      const s16x8 af = *(const s16x8*)(L + row * 64 + ((lg ^ (row & 3)) << 4));
#pragma unroll
      for (int t = 0; t < 4; ++t) {
        const int col = t * 16 + lr;
        const s16x8 bf = *(const s16x8*)(L + 4096 + col * 64 + ((lg ^ (col & 3)) << 4));
        MFMA16(acc[t], af, bf);
      }
    }
    asm volatile("s_waitcnt lgkmcnt(0)" ::: "memory");  // my ds_reads done
    __builtin_amdgcn_sched_barrier(0);
    __builtin_amdgcn_s_barrier();  // all waves done reading buf bi
    FENCE_ANCHOR();
    if (u + 3 < VSTEPS) stage(bi, s0 + u + 3);  // reuse buf; loads fly across barriers
    bi = (bi == 2) ? 0 : bi + 1;
  }

#pragma unroll
  for (int t = 0; t < 4; ++t) {
#pragma unroll
    for (int q = 0; q < 4; ++q) {
      const int c = 16 * t + cn[q];
      const int r = r0 + wv * 16 + cm[q];
      if (r < NN) atomicAdd(&Yf[(size_t)r * NCLS + c], acc[t][q]);
    }
  }
}

// ================ gmmf: filter pass — M=64, f32 A staged, 3-buf counted-vmcnt ================
// grid (157, 16, 2): z = filter. LDS 3 x 12KB (A 8KB XOR-8 + B 4KB).
// 3 global_load_lds per wave per stage -> vmcnt(6)/(3)/(0).
__global__ __launch_bounds__(256) void gmmf_kernel(
    const float* __restrict__ A0, const float* __restrict__ A1,
    const unsigned short* __restrict__ BT, float* __restrict__ out,
    const float* __restrict__ comb) {
  __shared__ unsigned char lds[3][12288];  // [buf][A:0..8191 | B:8192..12287]
  const int tid = threadIdx.x, wv = tid >> 6, lane = tid & 63;
  const int lr = lane & 15, lg = lane >> 4;
  const int r0 = blockIdx.x * 64;
  const int s0 = blockIdx.y * VSTEPS;
  const int z = blockIdx.z;
  const float* A = z ? A1 : A0;
  int cm[4], cn[4];
  calib_mn(lane, cm, cn);

  f32x4 acc[4];
#pragma unroll
  for (int t = 0; t < 4; ++t)
#pragma unroll
    for (int j = 0; j < 4; ++j) acc[t][j] = 0.f;

  const size_t alim = (size_t)NN * NN - 4;

  auto stage = [&](int b, int s) {
    const int k0 = s * 32;
#pragma unroll
    for (int i = 0; i < 2; ++i) {  // A f32: 512 units (8/row), chunk = slot ^ (row&7)
      const int U = i * 256 + wv * 64 + lane;
      const int row = U >> 3, slot = U & 7;
      const int chunk = slot ^ (row & 7);
      const int gr = (r0 + row < NN) ? (r0 + row) : (NN - 1);
      size_t off = (size_t)gr * NN + k0 + chunk * 4;
      if (off > alim) off = alim;  // k-pad clamp; B zeros kill the product
      __builtin_amdgcn_global_load_lds(A + off,
                                       (void*)&lds[b][(i * 256 + wv * 64) * 16], 16, 0, 0);
    }
    {  // B bf16: 256 units (4/col)
      const int V = wv * 64 + lane;
      const int col = V >> 2, slot = V & 3;
      const int chunk = slot ^ (col & 3);
      __builtin_amdgcn_global_load_lds(BT + (size_t)col * STRD + k0 + chunk * 8,
                                       (void*)&lds[b][8192 + wv * 1024], 16, 0, 0);
    }
  };

  stage(0, s0); stage(1, s0 + 1); stage(2, s0 + 2);

  int bi = 0;
  for (int u = 0; u < VSTEPS; ++u) {
    if (u + 2 < VSTEPS)      asm volatile("s_waitcnt vmcnt(6)" ::: "memory");
    else if (u + 1 < VSTEPS) asm volatile("s_waitcnt vmcnt(3)" ::: "memory");
    else                     asm volatile("s_waitcnt vmcnt(0)" ::: "memory");
    __builtin_amdgcn_sched_barrier(0);
    __builtin_amdgcn_s_barrier();
    FENCE_ANCHOR();
    {
      const unsigned char* L = lds[bi];
      const int row = wv * 16 + lr;
      s16x8 af;
#pragma unroll
      for (int d = 0; d < 2; ++d) {
        const int c = 2 * lg + d;
        const float4 f = *(const float4*)(L + row * 128 + ((c ^ (row & 7)) << 4));
        af[4 * d + 0] = (short)f2bf(f.x);
        af[4 * d + 1] = (short)f2bf(f.y);
        af[4 * d + 2] = (short)f2bf(f.z);
        af[4 * d + 3] = (short)f2bf(f.w);
      }
#pragma unroll
      for (int t = 0; t < 4; ++t) {
        const int col = t * 16 + lr;
        const s16x8 bf = *(const s16x8*)(L + 8192 + col * 64 + ((lg ^ (col & 3)) << 4));
        MFMA16(acc[t], af, bf);
      }
    }
    asm volatile("s_waitcnt lgkmcnt(0)" ::: "memory");
    __builtin_amdgcn_sched_barrier(0);
    __builtin_amdgcn_s_barrier();
    FENCE_ANCHOR();
    if (u + 3 < VSTEPS) stage(bi, s0 + u + 3);
    bi = (bi == 2) ? 0 : bi + 1;
  }

#pragma unroll
  for (int t = 0; t < 4; ++t) {
#pragma unroll
    for (int q = 0; q < 4; ++q) {
      const int c = 16 * t + cn[q];
      const int r = r0 + wv * 16 + cm[q];
      if (r < NN) atomicAdd(&out[(size_t)r * NCLS + c], comb[z * NCLS + c] * acc[t][q]);
    }
  }
}

// ---------------- finish: out += comb*Yf, PT = bf16(Yf^T), Yf = 0 ----------------
__global__ __launch_bounds__(256) void finish_old_kernel(
    float* __restrict__ Yf, const float* __restrict__ comb, int didx,
    unsigned short* __restrict__ PT, float* __restrict__ out) {
  __shared__ float ysh[32][65];
  const int tid = threadIdx.x;
  const int r0 = blockIdx.x * 32;
#pragma unroll
  for (int j = 0; j < 8; ++j) {
    const int idx = j * 256 + tid;
    const int rr = idx >> 6;
    const int c = idx & 63;
    const int r = r0 + rr;
    if (r < NN) {
      const float y = Yf[(size_t)r * NCLS + c];
      Yf[(size_t)r * NCLS + c] = 0.f;
      ysh[rr][c] = y;
      out[(size_t)r * NCLS + c] += comb[didx * NCLS + c] * y;
    }
  }
  __syncthreads();
  const int c = tid >> 2;
  const int rr = (tid & 3) * 8;
  if (r0 + rr + 7 < NN) {
    ushort4 u0 = make_ushort4(f2bf(ysh[rr + 0][c]), f2bf(ysh[rr + 1][c]),
                              f2bf(ysh[rr + 2][c]), f2bf(ysh[rr + 3][c]));
    ushort4 u1 = make_ushort4(f2bf(ysh[rr + 4][c]), f2bf(ysh[rr + 5][c]),
                              f2bf(ysh[rr + 6][c]), f2bf(ysh[rr + 7][c]));
    *(ushort4*)(PT + (size_t)c * STRD + r0 + rr) = u0;
    *(ushort4*)(PT + (size_t)c * STRD + r0 + rr + 4) = u1;
  }
}

extern "C" void kernel_launch(void* const* d_in, const int* in_sizes, int n_in,
                              void* d_out, int out_size, void* d_ws, size_t ws_size,
                              hipStream_t stream) {
  const float* x = (const float*)d_in[0];
  const float* adj = (const float*)d_in[1];
  const float* filt0 = (const float*)d_in[2];
  const float* filt1 = (const float*)d_in[3];
  const float* W1 = (const float*)d_in[4];
  const float* b1 = (const float*)d_in[5];
  const float* W2 = (const float*)d_in[6];
  const float* b2 = (const float*)d_in[7];
  const float* comb = (const float*)d_in[8];
  float* out = (float*)d_out;

  unsigned char* wsb = (unsigned char*)d_ws;
  size_t off = 0;
  auto carve = [&](size_t bytes) -> void* {
    void* p = wsb + off;
    off += (bytes + 255) & ~(size_t)255;
    return p;
  };
  unsigned short* W1T = (unsigned short*)carve((size_t)FEAT * HID * 2);
  unsigned short* W2T = (unsigned short*)carve((size_t)HID * NCLS * 2);
  unsigned short* H1 = (unsigned short*)carve((size_t)NN * HID * 2);
  float* Yf = (float*)carve((size_t)NN * NCLS * 4);
  unsigned short* HT = (unsigned short*)carve((size_t)NCLS * STRD * 2);
  unsigned short* pA = (unsigned short*)carve((size_t)NCLS * STRD * 2);
  unsigned short* pB = (unsigned short*)carve((size_t)NCLS * STRD * 2);
  unsigned short* adjb = (unsigned short*)carve((size_t)NN * STRD * 2);

  if (ws_size < off) {
    // Sentinel: absmax == 5.40625 exactly => ws too small.
    zero_f32_kernel<<<(out_size + 255) / 256, 256, 0, stream>>>(out, out_size);
    return;
  }

  zero_f32_kernel<<<(NN * NCLS + 255) / 256, 256, 0, stream>>>(Yf, NN * NCLS);
  prep_kernel<<<(FEAT * HID + 255) / 256, 256, 0, stream>>>(W1, W2, W1T, W2T, HT, pA, pB);
  mlp1_kernel<<<(NN + 15) / 16, 256, 0, stream>>>(x, W1T, b1, H1);
  mlp2_kernel<<<(NN + 15) / 16, 256, 0, stream>>>(H1, W2T, b2, comb, HT, out);
  cvt_adj_kernel<<<NN, 256, 0, stream>>>(adj, adjb);

  // filters (f32-staged, scaled atomics into out)
  gmmf_kernel<<<dim3(157, KSPLIT, 2), 256, 0, stream>>>(filt0, filt1, HT, out, comb);

  const unsigned short* pin = HT;
  for (int k = 1; k <= 10; ++k) {
    unsigned short* pout = (k & 1) ? pA : pB;
    gmm2_kernel<<<dim3(157, KSPLIT), 256, 0, stream>>>(adjb, pin, Yf);
    finish_old_kernel<<<313, 256, 0, stream>>>(Yf, comb, 2 + k, pout, out);
    pin = pout;
  }
}